// Round 1
// baseline (529.347 us; speedup 1.0000x reference)
//
#include <hip/hip_runtime.h>
#include <hip/hip_bf16.h>

// Problem constants (from reference): B=16, Lq=Lk=2048, D=128, fp32 in/out.
#define B_N   16
#define LL    2048
#define DD    128
#define NW    8                 // waves per workgroup
#define QBLK  16                // query rows per workgroup
#define KCOLS (LL / NW)         // 256 k-columns per wave
#define NT    (KCOLS / 16)      // 16 MFMA tiles per wave

typedef float f32x4  __attribute__((ext_vector_type(4)));
typedef short bf16x8 __attribute__((ext_vector_type(8)));

__device__ __forceinline__ short f2bf(float x) {
  union { float f; unsigned u; } v; v.f = x;
  unsigned r = (v.u + 0x7FFFu + ((v.u >> 16) & 1u)) >> 16;  // RNE
  return (short)r;
}

// ---- pre-pass 1: Q,K fp32 -> bf16 (row-major), vectorized ----
__global__ void cvt_qk(const float4* __restrict__ Q, const float4* __restrict__ K,
                       short4* __restrict__ Qb, short4* __restrict__ Kb, int nvec) {
  int stride = gridDim.x * blockDim.x;
  for (int i = blockIdx.x * blockDim.x + threadIdx.x; i < 2 * nvec; i += stride) {
    int sel = (i < nvec);
    int idx = sel ? i : i - nvec;
    float4 v = sel ? Q[idx] : K[idx];
    short4 o;
    o.x = f2bf(v.x); o.y = f2bf(v.y); o.z = f2bf(v.z); o.w = f2bf(v.w);
    if (sel) Qb[idx] = o; else Kb[idx] = o;
  }
}

// ---- pre-pass 2: V fp32 [B][L][D] -> bf16 transposed [B][D][L] ----
__global__ void transpose_v(const float* __restrict__ V, short* __restrict__ Vt) {
  __shared__ short t[32][33];   // +1 pad: conflict-free transpose
  int b = blockIdx.z, k0 = blockIdx.x * 32, d0 = blockIdx.y * 32;
  int tx = threadIdx.x, ty = threadIdx.y;
#pragma unroll
  for (int i = 0; i < 4; ++i) {
    int k = k0 + ty + i * 8;
    t[ty + i * 8][tx] = f2bf(V[((size_t)b * LL + k) * DD + d0 + tx]);
  }
  __syncthreads();
#pragma unroll
  for (int i = 0; i < 4; ++i) {
    int d = d0 + ty + i * 8;
    Vt[((size_t)b * DD + d) * LL + k0 + tx] = t[tx][ty + i * 8];
  }
}

// ---- main fused kernel: QK^T -> softmax -> write atten -> PV -> write ctx ----
__global__ __launch_bounds__(512) void attn_fused(
    const short* __restrict__ Qb, const short* __restrict__ Kb,
    const short* __restrict__ Vt, float* __restrict__ ctx,
    float* __restrict__ att) {
  __shared__ short Pl[QBLK * LL];     // 64 KiB normalized-P bf16 buffer
  __shared__ float redM[NW][QBLK];
  __shared__ float redS[NW][QBLK];

  const int tid  = threadIdx.x;
  const int lane = tid & 63;
  const int w    = tid >> 6;     // wave 0..7
  const int g    = lane >> 4;    // 0..3
  const int lr   = lane & 15;    // 0..15

  // XCD-friendly remap: each XCD (blockIdx%8) gets a contiguous chunk -> 2 batches/XCD in L2.
  const int wg    = ((blockIdx.x & 7) << 8) | (blockIdx.x >> 3);  // 2048 blocks, bijective
  const int batch = wg >> 7;            // /128
  const int q0    = (wg & 127) * QBLK;

  // Q fragments for this wave's 16 rows, all of D (A-frag: row=lane&15, k=(lane>>4)*8+j)
  const bf16x8* qp = (const bf16x8*)(Qb + (size_t)(batch * LL + q0 + lr) * DD);
  bf16x8 qf[4];
#pragma unroll
  for (int kk = 0; kk < 4; ++kk) qf[kk] = qp[kk * 4 + g];

  // ---- QK^T: 16 x 256 scores per wave, held in registers ----
  f32x4 s[NT];
#pragma unroll
  for (int t = 0; t < NT; ++t) s[t] = (f32x4){0.f, 0.f, 0.f, 0.f};

  const int c0w = w * KCOLS;
#pragma unroll
  for (int t = 0; t < NT; ++t) {
    const bf16x8* kp = (const bf16x8*)(Kb + (size_t)(batch * LL + c0w + t * 16 + lr) * DD);
#pragma unroll
    for (int kk = 0; kk < 4; ++kk)
      s[t] = __builtin_amdgcn_mfma_f32_16x16x32_bf16(qf[kk], kp[kk * 4 + g], s[t], 0, 0, 0);
  }

  // ---- softmax: row max (wave-local -> cross-wave via LDS) ----
  float m[4];
#pragma unroll
  for (int j = 0; j < 4; ++j) {
    float mm = s[0][j];
#pragma unroll
    for (int t = 1; t < NT; ++t) mm = fmaxf(mm, s[t][j]);
    mm = fmaxf(mm, __shfl_xor(mm, 1, 16));
    mm = fmaxf(mm, __shfl_xor(mm, 2, 16));
    mm = fmaxf(mm, __shfl_xor(mm, 4, 16));
    mm = fmaxf(mm, __shfl_xor(mm, 8, 16));
    m[j] = mm;
  }
  if (lr == 0) {
#pragma unroll
    for (int j = 0; j < 4; ++j) redM[w][4 * g + j] = m[j];
  }
  __syncthreads();

  // exp2-domain softmax: scale*log2(e) folded into one multiply
  const float SCALE2 = 0.08838834764831845f * 1.4426950408889634f;
  float gm[4], rs[4];
#pragma unroll
  for (int j = 0; j < 4; ++j) {
    float mm = redM[0][4 * g + j];
#pragma unroll
    for (int ww = 1; ww < NW; ++ww) mm = fmaxf(mm, redM[ww][4 * g + j]);
    gm[j] = mm * SCALE2;
    rs[j] = 0.f;
  }
#pragma unroll
  for (int t = 0; t < NT; ++t) {
#pragma unroll
    for (int j = 0; j < 4; ++j) {
      float p = exp2f(s[t][j] * SCALE2 - gm[j]);
      s[t][j] = p;
      rs[j] += p;
    }
  }
#pragma unroll
  for (int j = 0; j < 4; ++j) {
    float ss = rs[j];
    ss += __shfl_xor(ss, 1, 16);
    ss += __shfl_xor(ss, 2, 16);
    ss += __shfl_xor(ss, 4, 16);
    ss += __shfl_xor(ss, 8, 16);
    rs[j] = ss;
  }
  if (lr == 0) {
#pragma unroll
    for (int j = 0; j < 4; ++j) redS[w][4 * g + j] = rs[j];
  }
  __syncthreads();

  float rinv[4];
#pragma unroll
  for (int j = 0; j < 4; ++j) {
    float ss = redS[0][4 * g + j];
#pragma unroll
    for (int ww = 1; ww < NW; ++ww) ss += redS[ww][4 * g + j];
    rinv[j] = 1.0f / ss;
  }

  // ---- normalize, write atten (fp32), stash bf16 P into swizzled LDS ----
  float* attb = att + (size_t)batch * LL * LL;
#pragma unroll
  for (int t = 0; t < NT; ++t) {
#pragma unroll
    for (int j = 0; j < 4; ++j) {
      int r = 4 * g + j;
      int c = c0w + t * 16 + lr;
      float p = s[t][j] * rinv[j];
      attb[(size_t)(q0 + r) * LL + c] = p;
      int idx = r * LL + c;
      Pl[idx ^ ((r & 7) << 3)] = f2bf(p);   // XOR swizzle: conflict-free b128 reads
    }
  }
  __syncthreads();

  // ---- PV: wave w owns d-columns [16w,16w+16), full k=2048 ----
  f32x4 c2 = (f32x4){0.f, 0.f, 0.f, 0.f};
  const bf16x8* vp = (const bf16x8*)(Vt + (size_t)(batch * DD + w * 16 + lr) * LL);
#pragma unroll 8
  for (int kk = 0; kk < LL / 32; ++kk) {
    int ke = kk * 32 + g * 8;
    bf16x8 af = *(const bf16x8*)(Pl + ((lr * LL + ke) ^ ((lr & 7) << 3)));
    c2 = __builtin_amdgcn_mfma_f32_16x16x32_bf16(af, vp[kk * 4 + g], c2, 0, 0, 0);
  }

#pragma unroll
  for (int j = 0; j < 4; ++j)
    ctx[(size_t)(batch * LL + q0 + 4 * g + j) * DD + w * 16 + lr] = c2[j];
}

extern "C" void kernel_launch(void* const* d_in, const int* in_sizes, int n_in,
                              void* d_out, int out_size, void* d_ws, size_t ws_size,
                              hipStream_t stream) {
  const float* Q = (const float*)d_in[0];
  const float* K = (const float*)d_in[1];
  const float* V = (const float*)d_in[2];

  float* ctx = (float*)d_out;                       // [B][Lq][D]
  float* att = ctx + (size_t)B_N * LL * DD;         // [B][Lq][Lk]

  short* Qb = (short*)d_ws;                          // bf16 [B][L][D]
  short* Kb = Qb + (size_t)B_N * LL * DD;            // bf16 [B][L][D]
  short* Vt = Kb + (size_t)B_N * LL * DD;            // bf16 [B][D][L]

  const int nvec = B_N * LL * DD / 4;
  cvt_qk<<<2048, 256, 0, stream>>>((const float4*)Q, (const float4*)K,
                                   (short4*)Qb, (short4*)Kb, nvec);
  transpose_v<<<dim3(LL / 32, DD / 32, B_N), dim3(32, 8), 0, stream>>>(V, Vt);
  attn_fused<<<2048, 512, 0, stream>>>(Qb, Kb, Vt, ctx, att);
}